// Round 3
// baseline (234.930 us; speedup 1.0000x reference)
//
#include <hip/hip_runtime.h>
#include <hip/hip_bf16.h>

typedef unsigned short u16;
typedef __attribute__((ext_vector_type(8))) short short8;
typedef __attribute__((ext_vector_type(4))) float floatx4;

__device__ __forceinline__ u16 f32_to_bf16_rne(float f) {
  union { float f; unsigned int u; } v; v.f = f;
  unsigned int u = v.u;
  u += 0x7FFFu + ((u >> 16) & 1u);
  return (u16)(u >> 16);
}

__device__ __forceinline__ void load_lds_16(const void* gsrc, void* lds) {
  __builtin_amdgcn_global_load_lds(
      (const __attribute__((address_space(1))) unsigned int*)gsrc,
      (__attribute__((address_space(3))) unsigned int*)lds,
      16, 0, 0);
}

// ---------------- Kernel 1: global average pool ----------------
__global__ __launch_bounds__(256) void pool_kernel(const float* __restrict__ x,
                                                   float* __restrict__ pooled) {
  const int bc = blockIdx.x;
  const float4* row = (const float4*)(x + (size_t)bc * 3136);
  const int t = threadIdx.x;
  float s = 0.0f;
  for (int q = t; q < 784; q += 256) {
    float4 v = row[q];
    s += (v.x + v.y) + (v.z + v.w);
  }
  #pragma unroll
  for (int off = 32; off > 0; off >>= 1) s += __shfl_down(s, off, 64);
  __shared__ float red[4];
  if ((t & 63) == 0) red[t >> 6] = s;
  __syncthreads();
  if (t == 0) pooled[bc] = (red[0] + red[1] + red[2] + red[3]) * (1.0f / 3136.0f);
}

// ---------------- Kernel 2: attention MLP + w_dyn (bf16) ----------------
__global__ __launch_bounds__(256) void attn_wdyn_kernel(
    const float* __restrict__ pooled, const float* __restrict__ weights,
    const float* __restrict__ w1, const float* __restrict__ b1,
    const float* __restrict__ w2, const float* __restrict__ b2,
    u16* __restrict__ wdyn) {
  const int blk = blockIdx.x;
  const int b = blk >> 3;
  const int oc = blk & 7;
  const int t = threadIdx.x;
  __shared__ float ph[256];
  __shared__ float part[256];
  __shared__ float hb[64];
  __shared__ float lg[8];
  ph[t] = pooled[b * 256 + t];
  __syncthreads();
  {
    const int row = t >> 2, seg = t & 3;
    const float* wr = w1 + row * 256 + seg * 64;
    const float* pp = ph + seg * 64;
    float a = 0.0f;
    #pragma unroll 8
    for (int c = 0; c < 64; ++c) a += pp[c] * wr[c];
    part[t] = a;
  }
  __syncthreads();
  if (t < 64) {
    float a = part[t * 4] + part[t * 4 + 1] + part[t * 4 + 2] + part[t * 4 + 3] + b1[t];
    hb[t] = fmaxf(a, 0.0f);
  }
  __syncthreads();
  if (t < 64) {
    const int row = t >> 3, seg = t & 7;
    const float* wr = w2 + row * 64 + seg * 8;
    float a = 0.0f;
    #pragma unroll
    for (int j = 0; j < 8; ++j) a += hb[seg * 8 + j] * wr[j];
    part[t] = a;
  }
  __syncthreads();
  if (t < 8) {
    float a = b2[t];
    #pragma unroll
    for (int j = 0; j < 8; ++j) a += part[t * 8 + j];
    lg[t] = a;
  }
  __syncthreads();
  float a[8];
  {
    float mx = lg[0];
    #pragma unroll
    for (int e = 1; e < 8; ++e) mx = fmaxf(mx, lg[e]);
    float sum = 0.0f;
    #pragma unroll
    for (int e = 0; e < 8; ++e) { a[e] = __expf(lg[e] - mx); sum += a[e]; }
    float inv = 1.0f / sum;
    #pragma unroll
    for (int e = 0; e < 8; ++e) a[e] *= inv;
  }
  const int o0 = oc * 32;
  for (int i = 0; i < 32; ++i) {
    const int o = o0 + i;
    float acc = 0.0f;
    #pragma unroll
    for (int e = 0; e < 8; ++e)
      acc += a[e] * weights[((size_t)e * 256 + o) * 256 + t];
    wdyn[((size_t)b * 256 + o) * 256 + t] = f32_to_bf16_rne(acc);
  }
}

// ---------------- Kernel 3: batched GEMM out[b] = Wdyn[b] @ X[b] ----------------
// M=256, N=3136 (25 tiles of 128, last guarded), K=256.
// Tile 256x128x32; 4 waves, each owns 64m x 128n (4 mt x 8 nt of 16x16x32 MFMA).
#define BM 256
#define BN 128
#define BK 32
#define XP 40   // Xs pitch in u16 elements (80 B)

__global__ __launch_bounds__(256) void dynconv_gemm(const float* __restrict__ x,
                                                    const u16* __restrict__ wdyn,
                                                    float* __restrict__ out) {
  const int nb = blockIdx.x;   // 0..24
  const int b  = blockIdx.y;   // 0..31
  const int t = threadIdx.x;
  const int lane = t & 63;
  const int wv = t >> 6;
  const int quad = lane >> 4;
  const int l16 = lane & 15;

  __shared__ u16 Ws[BM * BK];    // [m][k], pitch 32 elems — lane-linear for load_lds
  __shared__ u16 Xs[BN * XP];    // [n][k], pitch 40 elems

  const float* xb = x + (size_t)b * (256 * 3136);
  const u16* wb = wdyn + (size_t)b * 256 * 256;
  float* ob = out + (size_t)b * 256 * 3136;
  const int n0 = nb * BN;

  floatx4 acc[4][8];
  #pragma unroll
  for (int i = 0; i < 4; ++i)
    #pragma unroll
    for (int j = 0; j < 8; ++j) acc[i][j] = (floatx4)(0.0f);

  // X staging: each thread owns n = lane and n = lane+64 within the tile,
  // 8 k-rows (wave wv covers rows wv*8..wv*8+7). Clamped for last tile.
  const int gn1 = min(n0 + lane, 3135);
  const int gn2 = min(n0 + lane + 64, 3135);

  for (int kt = 0; kt < 8; ++kt) {
    const int k0 = kt * BK;
    // ---- stage W tile via global_load_lds (lane-linear [m][k]) ----
    #pragma unroll
    for (int j = 0; j < 4; ++j) {
      const int i = j * 256 + t;   // 16B-chunk id 0..1023
      const int r = i >> 2;
      const int c8 = i & 3;
      load_lds_16(wb + r * 256 + k0 + c8 * 8, &Ws[i * 8]);
    }
    // ---- stage X tile: 2x8 coalesced fp32 loads, pk-cvt, 2 b128 LDS writes ----
    {
      const float* base = xb + (size_t)(k0 + wv * 8) * 3136;
      float v1[8], v2[8];
      #pragma unroll
      for (int j = 0; j < 8; ++j) {
        v1[j] = base[(size_t)j * 3136 + gn1];
        v2[j] = base[(size_t)j * 3136 + gn2];
      }
      short8 p1, p2;
      #pragma unroll
      for (int j = 0; j < 4; ++j) {
        __hip_bfloat162 h1 = __float22bfloat162_rn(make_float2(v1[2 * j], v1[2 * j + 1]));
        __hip_bfloat162 h2 = __float22bfloat162_rn(make_float2(v2[2 * j], v2[2 * j + 1]));
        union { __hip_bfloat162 h; struct { short lo, hi; } s; } u1, u2;
        u1.h = h1; u2.h = h2;
        p1[2 * j] = u1.s.lo; p1[2 * j + 1] = u1.s.hi;
        p2[2 * j] = u2.s.lo; p2[2 * j + 1] = u2.s.hi;
      }
      *(short8*)(&Xs[lane * XP + wv * 8]) = p1;
      *(short8*)(&Xs[(lane + 64) * XP + wv * 8]) = p2;
    }
    __syncthreads();
    // ---- MFMA: 4 m-tiles x 8 n-tiles per wave ----
    short8 bfr[8];
    #pragma unroll
    for (int nt = 0; nt < 8; ++nt) {
      const int n = nt * 16 + l16;
      bfr[nt] = *(const short8*)(&Xs[n * XP + quad * 8]);
    }
    #pragma unroll
    for (int mt = 0; mt < 4; ++mt) {
      const int r = wv * 64 + mt * 16 + l16;
      short8 af = *(const short8*)(&Ws[r * BK + quad * 8]);
      #pragma unroll
      for (int nt = 0; nt < 8; ++nt)
        acc[mt][nt] = __builtin_amdgcn_mfma_f32_16x16x32_bf16(
            af, bfr[nt], acc[mt][nt], 0, 0, 0);
    }
    __syncthreads();
  }
  // ---- epilogue: C/D layout col=lane&15 (n), row=quad*4+reg (m) ----
  #pragma unroll
  for (int mt = 0; mt < 4; ++mt) {
    const int orow = wv * 64 + mt * 16 + quad * 4;
    #pragma unroll
    for (int nt = 0; nt < 8; ++nt) {
      const int n = n0 + nt * 16 + l16;
      if (n < 3136) {
        #pragma unroll
        for (int r = 0; r < 4; ++r)
          ob[(size_t)(orow + r) * 3136 + n] = acc[mt][nt][r];
      }
    }
  }
}

extern "C" void kernel_launch(void* const* d_in, const int* in_sizes, int n_in,
                              void* d_out, int out_size, void* d_ws, size_t ws_size,
                              hipStream_t stream) {
  const float* x       = (const float*)d_in[0];
  const float* weights = (const float*)d_in[1];
  const float* w1      = (const float*)d_in[2];
  const float* b1      = (const float*)d_in[3];
  const float* w2      = (const float*)d_in[4];
  const float* b2      = (const float*)d_in[5];
  float* out = (float*)d_out;

  float* pooled = (float*)d_ws;                       // 32 KB
  u16* wdyn = (u16*)((char*)d_ws + 32768);            // 4 MB bf16 [32][256][256]

  pool_kernel<<<8192, 256, 0, stream>>>(x, pooled);
  attn_wdyn_kernel<<<256, 256, 0, stream>>>(pooled, weights, w1, b1, w2, b2, wdyn);
  dynconv_gemm<<<dim3(25, 32), 256, 0, stream>>>(x, wdyn, out);
}